// Round 1
// baseline (275.737 us; speedup 1.0000x reference)
//
#include <hip/hip_runtime.h>
#include <hip/hip_bf16.h>
#include <cstdint>

#define QMAXF 127.0f
#define EPSQ 1e-8f

typedef __bf16 bf16x8 __attribute__((ext_vector_type(8)));
typedef float f32x4 __attribute__((ext_vector_type(4)));

static constexpr int BB = 32;   // 2*16 batch
static constexpr int MM = 2048;
static constexpr int KK = 128;
static constexpr int NN = 2048;

// workspace layout (bytes)
static constexpr size_t OFF_Q1   = 0;                                  // ushort[B*M*K]  A as exact-int bf16
static constexpr size_t OFF_Q2T  = OFF_Q1  + (size_t)BB*MM*KK*2;       // ushort[B*N*K]  B dequant, transposed (k contig)
static constexpr size_t OFF_S1   = OFF_Q2T + (size_t)BB*NN*KK*2;       // float[B*M]
static constexpr size_t OFF_S2   = OFF_S1  + (size_t)BB*MM*4;          // float[B*K]
static constexpr size_t OFF_AMAX = OFF_S2  + (size_t)BB*KK*4;          // float[B*M]

// ---------------- quantize inputs1: per-row (K=128) amax; store int values as bf16 (exact) + s1 ----------------
__global__ __launch_bounds__(256) void quant_rows128(const float* __restrict__ x,
                                                     unsigned short* __restrict__ q,
                                                     float* __restrict__ s1) {
    int wave = threadIdx.x >> 6, lane = threadIdx.x & 63;
    int row = blockIdx.x * 4 + wave;               // 65536 rows
    const float2* xr = reinterpret_cast<const float2*>(x) + (size_t)row * 64;
    float2 v = xr[lane];
    float a = fmaxf(fabsf(v.x), fabsf(v.y));
#pragma unroll
    for (int m = 32; m; m >>= 1) a = fmaxf(a, __shfl_xor(a, m));
    float scale = fmaxf(a, EPSQ) / QMAXF;
    float i0 = fminf(fmaxf(rintf(v.x / scale), -128.f), 127.f);
    float i1 = fminf(fmaxf(rintf(v.y / scale), -128.f), 127.f);
    __bf16 h0 = (__bf16)i0, h1 = (__bf16)i1;       // integers <=128: exact
    ushort2 st;
    st.x = *reinterpret_cast<unsigned short*>(&h0);
    st.y = *reinterpret_cast<unsigned short*>(&h1);
    reinterpret_cast<ushort2*>(q + (size_t)row * 128)[lane] = st;
    if (lane == 0) s1[row] = scale;
}

// ---------------- inputs2: per-k-row (N=2048) amax -> s2 ----------------
__global__ __launch_bounds__(256) void amax_rows2048(const float* __restrict__ x,
                                                     float* __restrict__ s2) {
    int row = blockIdx.x;                          // B*K = 4096 rows
    const float4* xr = reinterpret_cast<const float4*>(x) + (size_t)row * 512;
    int t = threadIdx.x;
    float4 v0 = xr[t], v1 = xr[t + 256];
    float a = fmaxf(fmaxf(fmaxf(fabsf(v0.x), fabsf(v0.y)), fmaxf(fabsf(v0.z), fabsf(v0.w))),
                    fmaxf(fmaxf(fabsf(v1.x), fabsf(v1.y)), fmaxf(fabsf(v1.z), fabsf(v1.w))));
#pragma unroll
    for (int m = 32; m; m >>= 1) a = fmaxf(a, __shfl_xor(a, m));
    __shared__ float red[4];
    if ((t & 63) == 0) red[t >> 6] = a;
    __syncthreads();
    if (t == 0) {
        float m0 = fmaxf(fmaxf(red[0], red[1]), fmaxf(red[2], red[3]));
        s2[row] = fmaxf(m0, EPSQ) / QMAXF;
    }
}

// ---------------- inputs2: dequantize + transpose to q2t[b][n][k] (k contiguous, bf16) ----------------
__global__ __launch_bounds__(256) void quant_transpose(const float* __restrict__ x,
                                                       const float* __restrict__ s2,
                                                       unsigned short* __restrict__ q2t) {
    int b = blockIdx.x >> 5;
    int n0 = (blockIdx.x & 31) * 64;
    __shared__ unsigned short lds[64][136];
    int t = threadIdx.x;
    int rr = t >> 4, cc = t & 15;
#pragma unroll
    for (int p = 0; p < 8; ++p) {
        int k = p * 16 + rr;
        float s = s2[b * 128 + k];
        const float4* src = reinterpret_cast<const float4*>(x + ((size_t)b * 128 + k) * 2048 + n0);
        float4 v = src[cc];
        float f[4] = {v.x, v.y, v.z, v.w};
#pragma unroll
        for (int e = 0; e < 4; ++e) {
            float iq = fminf(fmaxf(rintf(f[e] / s), -128.f), 127.f);
            __bf16 h = (__bf16)(iq * s);
            lds[cc * 4 + e][k] = *reinterpret_cast<unsigned short*>(&h);
        }
    }
    __syncthreads();
    int nl = t >> 2, seg = t & 3;
    uint4* dst = reinterpret_cast<uint4*>(q2t + ((size_t)b * 2048 + n0 + nl) * 128 + seg * 32);
#pragma unroll
    for (int j = 0; j < 4; ++j)
        dst[j] = *reinterpret_cast<const uint4*>(&lds[nl][seg * 32 + j * 8]);
}

// ---------------- batched GEMM 128x128 tile, K=128 single stage.
// PASS 1: per-output-row amax (atomicMax).  PASS 2: recompute + fake-quant + store. ----------------
template <int PASS>
__global__ __launch_bounds__(256, 2) void gemm_kernel(const unsigned short* __restrict__ qa,
                                                      const unsigned short* __restrict__ qbt,
                                                      const float* __restrict__ s1,
                                                      float* __restrict__ amax,
                                                      float* __restrict__ out) {
    int blk = blockIdx.x;
    int b  = blk >> 8;
    int mt = (blk >> 4) & 15;
    int nt = blk & 15;

    __shared__ unsigned short As[128][136];   // padded: 272B row stride, 16B aligned
    __shared__ unsigned short Bs[128][136];
    __shared__ float sS1[128], sInv[128], sOsc[128];

    const uint4* Ag = reinterpret_cast<const uint4*>(qa + ((size_t)b * 2048 + mt * 128) * 128);
    const uint4* Bg = reinterpret_cast<const uint4*>(qbt + ((size_t)b * 2048 + nt * 128) * 128);
#pragma unroll
    for (int i = 0; i < 8; ++i) {
        int c = i * 256 + threadIdx.x;        // 2048 16B chunks per tile
        int row = c >> 4, col = (c & 15) << 3;
        *reinterpret_cast<uint4*>(&As[row][col]) = Ag[c];
        *reinterpret_cast<uint4*>(&Bs[row][col]) = Bg[c];
    }
    if (PASS == 2 && threadIdx.x < 128) {
        int grow = mt * 128 + threadIdx.x;
        float s1v = s1[b * 2048 + grow];
        float am = amax[b * 2048 + grow] * s1v;
        float osc = fmaxf(am, EPSQ) / QMAXF;
        sS1[threadIdx.x] = s1v;
        sOsc[threadIdx.x] = osc;
        sInv[threadIdx.x] = 1.0f / osc;
    }
    __syncthreads();

    int wave = threadIdx.x >> 6, lane = threadIdx.x & 63;
    int wm = wave >> 1, wn = wave & 1;        // 2x2 waves, 64x64 each
    int lr = lane & 15, lg = lane >> 4;

    f32x4 acc[4][4];
#pragma unroll
    for (int mi = 0; mi < 4; ++mi)
#pragma unroll
        for (int ni = 0; ni < 4; ++ni) {
            f32x4 z = {0.f, 0.f, 0.f, 0.f};
            acc[mi][ni] = z;
        }

#pragma unroll
    for (int ks = 0; ks < 4; ++ks) {
        bf16x8 af[4], bfr[4];
#pragma unroll
        for (int mi = 0; mi < 4; ++mi)
            af[mi] = *reinterpret_cast<const bf16x8*>(&As[wm * 64 + mi * 16 + lr][ks * 32 + lg * 8]);
#pragma unroll
        for (int ni = 0; ni < 4; ++ni)
            bfr[ni] = *reinterpret_cast<const bf16x8*>(&Bs[wn * 64 + ni * 16 + lr][ks * 32 + lg * 8]);
#pragma unroll
        for (int mi = 0; mi < 4; ++mi)
#pragma unroll
            for (int ni = 0; ni < 4; ++ni)
                acc[mi][ni] = __builtin_amdgcn_mfma_f32_16x16x32_bf16(af[mi], bfr[ni], acc[mi][ni], 0, 0, 0);
    }

    if (PASS == 1) {
#pragma unroll
        for (int mi = 0; mi < 4; ++mi) {
#pragma unroll
            for (int r = 0; r < 4; ++r) {
                float v = 0.f;
#pragma unroll
                for (int ni = 0; ni < 4; ++ni) v = fmaxf(v, fabsf(acc[mi][ni][r]));
                v = fmaxf(v, __shfl_xor(v, 1));
                v = fmaxf(v, __shfl_xor(v, 2));
                v = fmaxf(v, __shfl_xor(v, 4));
                v = fmaxf(v, __shfl_xor(v, 8));
                if (lr == r) {  // raw amax (>=0): uint compare == float compare
                    int grow = mt * 128 + wm * 64 + mi * 16 + lg * 4 + r;
                    atomicMax(reinterpret_cast<unsigned*>(&amax[b * 2048 + grow]),
                              __float_as_uint(v));
                }
            }
        }
    } else {
        size_t ob = (size_t)b * 2048 * 2048;
#pragma unroll
        for (int mi = 0; mi < 4; ++mi) {
#pragma unroll
            for (int r = 0; r < 4; ++r) {
                int lrow = wm * 64 + mi * 16 + lg * 4 + r;
                float s1v = sS1[lrow], inv = sInv[lrow], osc = sOsc[lrow];
                size_t rowoff = ob + (size_t)(mt * 128 + lrow) * 2048 + nt * 128 + wn * 64 + lr;
#pragma unroll
                for (int ni = 0; ni < 4; ++ni) {
                    float c = acc[mi][ni][r] * s1v;
                    float q = fminf(fmaxf(rintf(c * inv), -128.f), 127.f) * osc;
                    out[rowoff + ni * 16] = q;
                }
            }
        }
    }
}

extern "C" void kernel_launch(void* const* d_in, const int* in_sizes, int n_in,
                              void* d_out, int out_size, void* d_ws, size_t ws_size,
                              hipStream_t stream) {
    const float* in1 = (const float*)d_in[0];  // [2,16,2048,128]
    const float* in2 = (const float*)d_in[1];  // [2,16,128,2048]
    char* ws = (char*)d_ws;
    unsigned short* q1  = (unsigned short*)(ws + OFF_Q1);
    unsigned short* q2t = (unsigned short*)(ws + OFF_Q2T);
    float* s1   = (float*)(ws + OFF_S1);
    float* s2   = (float*)(ws + OFF_S2);
    float* amax = (float*)(ws + OFF_AMAX);
    float* out  = (float*)d_out;

    hipMemsetAsync(amax, 0, (size_t)BB * MM * 4, stream);
    quant_rows128 <<<BB * MM / 4, 256, 0, stream>>>(in1, q1, s1);
    amax_rows2048 <<<BB * KK,     256, 0, stream>>>(in2, s2);
    quant_transpose<<<BB * (NN / 64), 256, 0, stream>>>(in2, s2, q2t);
    gemm_kernel<1><<<BB * 256, 256, 0, stream>>>(q1, q2t, s1, amax, out);
    gemm_kernel<2><<<BB * 256, 256, 0, stream>>>(q1, q2t, s1, amax, out);
}